// Round 1
// baseline (447.635 us; speedup 1.0000x reference)
//
#include <hip/hip_runtime.h>

#define H 128
#define W 128
#define RR 32            // output rows per 32-lane group
#define GPI (H / RR)     // row-groups per image = 4

// One 32-lane group handles a 32-row strip of one 128x128 image.
// Each lane owns 4 consecutive x-pixels (float4). Rolling input-stationary
// scheme: each input row feeds 5 in-flight output-row accumulators.
__global__ __launch_bounds__(256, 4) void blur5x5_kernel(
        const float* __restrict__ x,
        const float* __restrict__ p_lls,
        float* __restrict__ out,
        int n_groups) {

    // ---- 5x5 weight table (per-thread, one-time; matches jnp reference) ----
    float ls2 = 2.0f * expf(p_lls[0]);
    float w[5][5];
    float wsum = 0.0f;
    #pragma unroll
    for (int i = 0; i < 5; ++i) {
        #pragma unroll
        for (int j = 0; j < 5; ++j) {
            float cx = (float)(i - 2);
            float cy = (float)(j - 2);
            float q  = cx * cx + cy * cy;
            float u  = expf(-(q * q) / ls2);
            w[i][j] = u;
            wsum += u;
        }
    }
    float winv = 1.0f / wsum;
    #pragma unroll
    for (int i = 0; i < 5; ++i) {
        #pragma unroll
        for (int j = 0; j < 5; ++j) w[i][j] *= winv;
    }

    // ---- group / lane mapping ----
    int gib   = threadIdx.x >> 5;                      // group in block (0..7)
    int wl    = threadIdx.x & 31;                      // lane in group
    int group = blockIdx.x * (blockDim.x >> 5) + gib;
    if (group >= n_groups) return;
    int img = group / GPI;
    int rg  = group - img * GPI;
    int r0  = rg * RR;

    const float* ib = x   + (size_t)img * (H * W);
    float*       ob = out + (size_t)img * (H * W);
    int xc = wl * 4;

    // acc[d] holds out row (yi - 2 + d) while processing input row yi
    float acc[5][4];
    #pragma unroll
    for (int d = 0; d < 5; ++d) {
        #pragma unroll
        for (int p = 0; p < 4; ++p) acc[d][p] = 0.0f;
    }

    #pragma unroll 6
    for (int i = 0; i < RR + 4; ++i) {    // input rows r0-2 .. r0+RR+1
        int yi = r0 - 2 + i;
        float4 v = make_float4(0.0f, 0.0f, 0.0f, 0.0f);
        if (yi >= 0 && yi < H)
            v = *reinterpret_cast<const float4*>(ib + yi * W + xc);

        // W-halo from neighbor lanes (width-32 sub-wave shuffles)
        float l2 = __shfl_up(v.z, 1, 32);
        float l3 = __shfl_up(v.w, 1, 32);
        float r4 = __shfl_down(v.x, 1, 32);
        float r5 = __shfl_down(v.y, 1, 32);
        if (wl == 0)  { l2 = 0.0f; l3 = 0.0f; }   // zero pad left image edge
        if (wl == 31) { r4 = 0.0f; r5 = 0.0f; }   // zero pad right image edge
        float win[8] = { l2, l3, v.x, v.y, v.z, v.w, r4, r5 };

        // input row yi contributes to out rows yi-2..yi+2 with weight row 4-d
        #pragma unroll
        for (int d = 0; d < 5; ++d) {
            const int t = 4 - d;
            #pragma unroll
            for (int p = 0; p < 4; ++p) {
                float s = acc[d][p];
                #pragma unroll
                for (int dx = 0; dx < 5; ++dx)
                    s = fmaf(w[t][dx], win[p + dx], s);
                acc[d][p] = s;
            }
        }

        // out row r0+i-4 is complete
        if (i >= 4) {
            float4 o = make_float4(acc[0][0], acc[0][1], acc[0][2], acc[0][3]);
            *reinterpret_cast<float4*>(ob + (size_t)(r0 + i - 4) * W + xc) = o;
        }

        // shift ring (static indices -> register renaming, no scratch)
        #pragma unroll
        for (int d = 0; d < 4; ++d) {
            #pragma unroll
            for (int p = 0; p < 4; ++p) acc[d][p] = acc[d + 1][p];
        }
        #pragma unroll
        for (int p = 0; p < 4; ++p) acc[4][p] = 0.0f;
    }
}

extern "C" void kernel_launch(void* const* d_in, const int* in_sizes, int n_in,
                              void* d_out, int out_size, void* d_ws, size_t ws_size,
                              hipStream_t stream) {
    (void)n_in; (void)out_size; (void)d_ws; (void)ws_size;
    const float* x   = (const float*)d_in[0];
    const float* lls = (const float*)d_in[1];
    float* out = (float*)d_out;

    int n_img    = in_sizes[0] / (H * W);   // 4096
    int n_groups = n_img * GPI;             // 16384
    int threads  = 256;
    int gpb      = threads / 32;            // 8 groups per block
    int blocks   = (n_groups + gpb - 1) / gpb;

    blur5x5_kernel<<<blocks, threads, 0, stream>>>(x, lls, out, n_groups);
}